// Round 1
// 371.867 us; speedup vs baseline: 1.2140x; 1.2140x over previous
//
#include <hip/hip_runtime.h>

#define T_STEPS 512
#define BT 16          // batches per block (one 16-col MFMA tile, batch = l15)
#define XSTRIDE 524    // padded x row stride (floats)
#define HSTRIDE 72     // padded h row stride (shorts); 144B rows, 16B aligned

typedef __attribute__((ext_vector_type(8))) short bf16x8;
typedef __attribute__((ext_vector_type(4))) float f32x4;
typedef __attribute__((ext_vector_type(2))) unsigned u32x2;

__device__ __forceinline__ short f2bf(float f) {
    union { float f; unsigned u; } v; v.f = f;
    unsigned r = v.u + 0x7fffu + ((v.u >> 16) & 1u);   // RNE
    return (short)(r >> 16);
}
__device__ __forceinline__ float bf2f(short s) {
    union { float f; unsigned u; } v;
    v.u = ((unsigned)(unsigned short)s) << 16;
    return v.f;
}
__device__ __forceinline__ float ubits(unsigned u) {
    union { unsigned u; float f; } v; v.u = u; return v.f;
}
__device__ __forceinline__ float exp2_fast(float x) {
#if __has_builtin(__builtin_amdgcn_exp2f)
    return __builtin_amdgcn_exp2f(x);
#else
    return __expf(x * 0.69314718056f);
#endif
}

#define L2E 1.44269504089f

__global__ __launch_bounds__(256, 1) void lstm_persist(
    const float* __restrict__ x,      // [B, T] (IN=1 folded)
    const float* __restrict__ W_ih,   // [256]
    const float* __restrict__ W_hh,   // [256,64]
    const float* __restrict__ b_ih,   // [256]
    const float* __restrict__ b_hh,   // [256]
    const float* __restrict__ W_fc,   // [64]
    const float* __restrict__ b_fc,   // [1]
    float* __restrict__ out)          // [B]
{
    __shared__ __align__(16) float x_lds[BT * XSTRIDE];
    __shared__ __align__(16) short hbuf[2][2][BT][HSTRIDE]; // [buf][hi/lo][b][k]

    const int tid  = threadIdx.x;
    const int wave = tid >> 6;     // 0..3  -> k-block w: k in [16w, 16w+16)
    const int lane = tid & 63;
    const int l15  = lane & 15;    // batch index (output col after swap)
    const int quad = lane >> 4;    // 0..3
    const int b0   = blockIdx.x * BT;

    // ---- stage x[b0..b0+15][0..511] into LDS (coalesced float4) ----
    {
        const float* xg = x + (size_t)b0 * T_STEPS;
        #pragma unroll
        for (int i = 0; i < 8; ++i) {
            int f4 = tid + i * 256;        // 0..2047 float4 chunks
            int b  = f4 >> 7;              // 128 float4 per row
            int t4 = f4 & 127;
            float4 v = reinterpret_cast<const float4*>(xg + (size_t)b * T_STEPS)[t4];
            reinterpret_cast<float4*>(&x_lds[b * XSTRIDE + t4 * 4])[0] = v;
        }
    }
    // ---- zero h buffer 0 (hi+lo) ----
    {
        short* p = &hbuf[0][0][0][0];
        for (int i = tid; i < 2 * BT * HSTRIDE; i += 256) p[i] = 0;
    }

    // ---- per-lane resident W_hh fragments (split bf16), bias, W_ih ----
    // SWAPPED operands: A = W (rows = gate dim), B = h^T (cols = batch).
    // A-frag: lane holds A[m=l15][k=quad*8+j] = W_hh[g*64+wave*16+l15][kh*32+quad*8+j]
    // (identical per-lane data/addressing to the old B-frag).
    bf16x8 Whi[4][2], Wlo[4][2];
    float bias[4][4], wih[4][4];
    #pragma unroll
    for (int g = 0; g < 4; ++g) {
        int na = g * 64 + wave * 16 + l15;
        #pragma unroll
        for (int kh = 0; kh < 2; ++kh) {
            const float* wr = W_hh + na * 64 + kh * 32 + quad * 8;
            bf16x8 hi, lo;
            #pragma unroll
            for (int j = 0; j < 8; ++j) {
                float w = wr[j];
                short h16 = f2bf(w);
                hi[j] = h16;
                lo[j] = f2bf(w - bf2f(h16));
            }
            Whi[g][kh] = hi;
            Wlo[g][kh] = lo;
        }
        // D layout: col = l15 (batch), row = quad*4 + r (gate-local) ->
        // this lane owns gate g, k_hidden = wave*16 + quad*4 + r, batch l15.
        #pragma unroll
        for (int r = 0; r < 4; ++r) {
            int n = g * 64 + wave * 16 + quad * 4 + r;
            bias[g][r] = b_ih[n] + b_hh[n];
            wih[g][r]  = W_ih[n];
        }
    }

    float c[4] = {0.f, 0.f, 0.f, 0.f};
    const int hoff = l15 * HSTRIDE + quad * 8;               // B-frag read (shorts), same as before
    const int woff = l15 * HSTRIDE + wave * 16 + quad * 4;   // packed write: 4 consecutive k
    const float* xrow = &x_lds[l15 * XSTRIDE];

    __syncthreads();

    #pragma unroll 2
    for (int t = 0; t < T_STEPS; ++t) {
        const int rb = t & 1, wb = rb ^ 1;

        // B fragments: h_hi/h_lo (8 consecutive bf16 per lane), kh = 0 / +32
        const short* hhi = &hbuf[rb][0][0][0];
        const short* hlo = &hbuf[rb][1][0][0];
        bf16x8 bhi0 = *reinterpret_cast<const bf16x8*>(hhi + hoff);
        bf16x8 bhi1 = *reinterpret_cast<const bf16x8*>(hhi + hoff + 32);
        bf16x8 blo0 = *reinterpret_cast<const bf16x8*>(hlo + hoff);
        bf16x8 blo1 = *reinterpret_cast<const bf16x8*>(hlo + hoff + 32);

        // batch is lane-uniform across r now: ONE x load
        float xv = xrow[t];

        f32x4 acc[4];
        #pragma unroll
        for (int g = 0; g < 4; ++g) {
            #pragma unroll
            for (int r = 0; r < 4; ++r)
                acc[g][r] = fmaf(wih[g][r], xv, bias[g][r]);
        }
        // same 6-term split order as before -> gate values bitwise identical
        #pragma unroll
        for (int g = 0; g < 4; ++g) {
            acc[g] = __builtin_amdgcn_mfma_f32_16x16x32_bf16(Whi[g][0], bhi0, acc[g], 0, 0, 0);
            acc[g] = __builtin_amdgcn_mfma_f32_16x16x32_bf16(Whi[g][1], bhi1, acc[g], 0, 0, 0);
            acc[g] = __builtin_amdgcn_mfma_f32_16x16x32_bf16(Whi[g][0], blo0, acc[g], 0, 0, 0);
            acc[g] = __builtin_amdgcn_mfma_f32_16x16x32_bf16(Whi[g][1], blo1, acc[g], 0, 0, 0);
            acc[g] = __builtin_amdgcn_mfma_f32_16x16x32_bf16(Wlo[g][0], bhi0, acc[g], 0, 0, 0);
            acc[g] = __builtin_amdgcn_mfma_f32_16x16x32_bf16(Wlo[g][1], bhi1, acc[g], 0, 0, 0);
        }

        // activations + cell update, division-refactored: 5 exp + 2 rcp per (b,k)
        // c' = (c*Ai*Ag + sign(g)(1-eg)*Af) / (Ai*Af*Ag); h = sign(c')(1-ec)/(Ao*(1+ec))
        float hv[4];
        #pragma unroll
        for (int r = 0; r < 4; ++r) {
            float iv = acc[0][r], fv = acc[1][r], gv = acc[2][r], ov = acc[3][r];
            float ei = exp2_fast(iv * (-L2E));
            float ef = exp2_fast(fv * (-L2E));
            float eg = exp2_fast(fabsf(gv) * (-2.0f * L2E));   // <= 1, overflow-safe
            float eo = exp2_fast(ov * (-L2E));
            float Ai = 1.0f + ei, Af = 1.0f + ef, Ag = 1.0f + eg, Ao = 1.0f + eo;
            float tg = copysignf(1.0f - eg, gv);
            float P  = Ai * Ag;
            float num = fmaf(c[r], P, tg * Af);
            float cn  = num * __builtin_amdgcn_rcpf(P * Af);
            c[r] = cn;
            float ec = exp2_fast(fabsf(cn) * (-2.0f * L2E));   // <= 1, overflow-safe
            float tc = copysignf(1.0f - ec, cn);
            hv[r] = tc * __builtin_amdgcn_rcpf(Ao * (1.0f + ec));
        }

        // pack 4 consecutive k as bf16 pairs (HW RNE) + exact lo residuals,
        // 2x ds_write_b64 instead of 8x ds_write_b16
        unsigned hi0, hi1, lo0, lo1;
        asm("v_cvt_pk_bf16_f32 %0, %1, %2" : "=v"(hi0) : "v"(hv[0]), "v"(hv[1]));
        asm("v_cvt_pk_bf16_f32 %0, %1, %2" : "=v"(hi1) : "v"(hv[2]), "v"(hv[3]));
        float l0f = hv[0] - ubits(hi0 << 16);
        float l1f = hv[1] - ubits(hi0 & 0xffff0000u);
        float l2f = hv[2] - ubits(hi1 << 16);
        float l3f = hv[3] - ubits(hi1 & 0xffff0000u);
        asm("v_cvt_pk_bf16_f32 %0, %1, %2" : "=v"(lo0) : "v"(l0f), "v"(l1f));
        asm("v_cvt_pk_bf16_f32 %0, %1, %2" : "=v"(lo1) : "v"(l2f), "v"(l3f));
        u32x2 vhi = {hi0, hi1};
        u32x2 vlo = {lo0, lo1};
        *reinterpret_cast<u32x2*>(&hbuf[wb][0][0][0] + woff) = vhi;
        *reinterpret_cast<u32x2*>(&hbuf[wb][1][0][0] + woff) = vlo;

        __syncthreads();   // h(t+1) visible; also protects next step's overwrite of rb
    }

    // ---- final FC: out[b] = sum_k h[b][k]*W_fc[k] + b_fc  (h = buf 0 after t=511) ----
    if (tid < 16) {
        int b = tid;
        float s = b_fc[0];
        #pragma unroll 4
        for (int k = 0; k < 64; ++k) {
            float hv = bf2f(hbuf[0][0][b][k]) + bf2f(hbuf[0][1][b][k]);
            s += hv * W_fc[k];
        }
        out[b0 + b] = s;
    }
}

extern "C" void kernel_launch(void* const* d_in, const int* in_sizes, int n_in,
                              void* d_out, int out_size, void* d_ws, size_t ws_size,
                              hipStream_t stream) {
    const float* x    = (const float*)d_in[0];
    const float* W_ih = (const float*)d_in[1];
    const float* W_hh = (const float*)d_in[2];
    const float* b_ih = (const float*)d_in[3];
    const float* b_hh = (const float*)d_in[4];
    const float* W_fc = (const float*)d_in[5];
    const float* b_fc = (const float*)d_in[6];
    float* out = (float*)d_out;
    const int B = in_sizes[0] / T_STEPS;   // 4096
    lstm_persist<<<dim3(B / BT), dim3(256), 0, stream>>>(
        x, W_ih, W_hh, b_ih, b_hh, W_fc, b_fc, out);
}